// Round 5
// baseline (41.616 us; speedup 1.0000x reference)
//
#include <hip/hip_runtime.h>
#include <stdint.h>

#define NBOX 8192

// ws layout: float4 sbox[8192] (128 KB) then uint32_t flags[256] (1 KB).

// ---------------------------------------------------------------------------
// Kernel 1: stable rank by (desc score, asc index); scatter boxes as float4
// into sorted order; block 0 zeroes the suppress-flag bitmap.
// rank(e) = #{i: bits_i > bits_e} + #{i < e: bits_i == bits_e}
// (exactly jnp.argsort(-score) stable order; scores >= 0 so bits monotone).
// u32 keys in LDS (32 KB), uint4 reads = 4 keys/inst -> half the LDS bytes
// of the u64-key version (LDS-delivery-bound: ~5 us floor).
// ---------------------------------------------------------------------------
__global__ __launch_bounds__(256) void nms_rank_kernel(
    const float4* __restrict__ bbox, const uint32_t* __restrict__ scoreBits,
    float4* __restrict__ sbox, uint32_t* __restrict__ flags)
{
    __shared__ uint32_t keys[NBOX];          // 32 KB
    const int t = threadIdx.x;
    if (blockIdx.x == 0) flags[t] = 0;       // 256 words

    #pragma unroll
    for (int s = 0; s < NBOX / 1024; ++s)    // 8 x uint4 = 8192 keys
        ((uint4*)keys)[t + s * 256] = ((const uint4*)scoreBits)[t + s * 256];
    __syncthreads();

    const int e = blockIdx.x * 16 + (t >> 4);  // element this 16-thread group owns
    const int p = t & 15;
    const uint32_t m = keys[e];
    int cnt = 0;
    #pragma unroll 4
    for (int s = 0; s < NBOX / 64; ++s) {
        uint4 kb = ((const uint4*)keys)[s * 16 + p];   // keys 64s+4p .. +3
        int ib = s * 64 + p * 4;
        cnt += (int)(kb.x > m) + (int)((kb.x == m) & (ib + 0 < e));
        cnt += (int)(kb.y > m) + (int)((kb.y == m) & (ib + 1 < e));
        cnt += (int)(kb.z > m) + (int)((kb.z == m) & (ib + 2 < e));
        cnt += (int)(kb.w > m) + (int)((kb.w == m) & (ib + 3 < e));
    }
    cnt += __shfl_down(cnt, 8, 16);
    cnt += __shfl_down(cnt, 4, 16);
    cnt += __shfl_down(cnt, 2, 16);
    cnt += __shfl_down(cnt, 1, 16);

    if (p == 0) sbox[cnt] = bbox[e];           // unique rank, one dwordx4 store
}

// ---------------------------------------------------------------------------
// Kernel 2: suppression, triangular task grid. Wave-task w in [0,8704) maps
// to (is, jg) with jg >= 64*is (only sub-diagonal work; no early-exit waves).
// Within an is-band, jg DESCENDS -> heaviest tasks dispatch first, light
// diagonal tasks form the tail. Block = 4 consecutive waves = same i-slice
// (L1 reuse). 2-deep register load ring hides L1/L2 latency. Hot loop is
// branch-free; __ballot-accumulated conservative prefilter
// inter > 0.4110*ia + 0.4110*ja  (union >= 256, 0.4110 < 0.7/1.7*(1-3e-7),
// so no true IoU>0.7 hit is ever missed); exact IEEE-f32 reference math
// (incl. division) only on the rare candidate path.
// ---------------------------------------------------------------------------
__global__ __launch_bounds__(256, 4) void nms_suppress_kernel(
    const float4* __restrict__ sbox, uint32_t* __restrict__ flags)
{
    const int lane = (int)(threadIdx.x & 63);
    const int w    = (int)(blockIdx.x * 4 + (threadIdx.x >> 6)); // 0..8703

    // invert triangular index: band sizes 1024-64*is, is = 0..15
    int is = 0, rem = w;
    while (rem >= 1024 - 64 * is) { rem -= 1024 - 64 * is; ++is; }
    const int jg = 1023 - rem;               // heavy-first within band
    const int j0 = jg * 8;
    const int s0 = is * 512;                 // s0 <= j0 by construction

    int nfull = (j0 - s0) >> 6;              // chunks with all i < j0
    if (nfull > 8) nfull = 8;
    const int pc = nfull;                    // diagonal (masked) chunk index
    const bool partial = (pc < 8) && (s0 + pc * 64 < j0 + 7);

    float jy1[8], jx1[8], jy2[8], jx2[8], ja[8], tk[8];
    #pragma unroll
    for (int k = 0; k < 8; ++k) {
        float4 b = sbox[j0 + k];
        jy1[k] = b.x; jx1[k] = b.y; jy2[k] = b.z; jx2[k] = b.w;
        ja[k] = (b.z - b.x) * (b.w - b.y);   // same fp op order as reference
        tk[k] = 0.4110f * ja[k];
    }

    uint32_t hit = 0;
    // 2-deep ring; every index is min(.,pc): 64-aligned base <= j0 <= 8184
    // -> base <= 8128 -> base+lane <= 8191 (in-bounds always).
    float4 A = sbox[s0 + lane];
    float4 B = sbox[s0 + (pc > 0 ? 64 : 0) + lane];

    for (int c = 0; c < nfull; ++c) {
        int nidx = c + 2; if (nidx > pc) nidx = pc;
        float4 N = sbox[s0 + nidx * 64 + lane];

        const float iy1 = A.x, ix1 = A.y, iy2 = A.z, ix2 = A.w;
        const float ia  = (iy2 - iy1) * (ix2 - ix1);
        const float tia = 0.4110f * ia;

        unsigned long long candm = 0;
        #pragma unroll
        for (int k = 0; k < 8; ++k) {
            float ty1 = fmaxf(iy1, jy1[k]);
            float tx1 = fmaxf(ix1, jx1[k]);
            float ty2 = fminf(iy2, jy2[k]);
            float tx2 = fminf(ix2, jx2[k]);
            float ih = fmaxf(ty2 - ty1, 0.0f);
            float iw = fmaxf(tx2 - tx1, 0.0f);
            float inter = ih * iw;
            candm |= __ballot(inter > tia + tk[k]);
        }
        if (candm) {                          // rare: exact reference math
            #pragma unroll
            for (int k = 0; k < 8; ++k) {
                float ty1 = fmaxf(iy1, jy1[k]);
                float tx1 = fmaxf(ix1, jx1[k]);
                float ty2 = fminf(iy2, jy2[k]);
                float tx2 = fminf(ix2, jx2[k]);
                float ih = fmaxf(ty2 - ty1, 0.0f);
                float iw = fmaxf(tx2 - tx1, 0.0f);
                float inter = ih * iw;
                float s  = ia + ja[k];
                float un = s - inter;         // fl(fl(ai+aj)-inter), as ref
                float iou = inter / fmaxf(un, 1e-9f);
                if (iou > 0.7f) hit |= (1u << k);
            }
        }
        A = B; B = N;
    }

    if (partial) {                            // A holds chunk pc
        const int i = s0 + pc * 64 + lane;    // <= 8191 (see bound above)
        const float iy1 = A.x, ix1 = A.y, iy2 = A.z, ix2 = A.w;
        const float ia  = (iy2 - iy1) * (ix2 - ix1);
        const float tia = 0.4110f * ia;

        unsigned long long candm = 0;
        #pragma unroll
        for (int k = 0; k < 8; ++k) {
            float ty1 = fmaxf(iy1, jy1[k]);
            float tx1 = fmaxf(ix1, jx1[k]);
            float ty2 = fminf(iy2, jy2[k]);
            float tx2 = fminf(ix2, jx2[k]);
            float ih = fmaxf(ty2 - ty1, 0.0f);
            float iw = fmaxf(tx2 - tx1, 0.0f);
            float inter = ih * iw;
            candm |= __ballot((i < j0 + k) & (inter > tia + tk[k]));
        }
        if (candm) {
            #pragma unroll
            for (int k = 0; k < 8; ++k) {
                float ty1 = fmaxf(iy1, jy1[k]);
                float tx1 = fmaxf(ix1, jx1[k]);
                float ty2 = fminf(iy2, jy2[k]);
                float tx2 = fminf(ix2, jx2[k]);
                float ih = fmaxf(ty2 - ty1, 0.0f);
                float iw = fmaxf(tx2 - tx1, 0.0f);
                float inter = ih * iw;
                float s  = ia + ja[k];
                float un = s - inter;
                float iou = inter / fmaxf(un, 1e-9f);
                if ((i < j0 + k) & (iou > 0.7f)) hit |= (1u << k);
            }
        }
    }

    uint32_t byte = 0;
    #pragma unroll
    for (int k = 0; k < 8; ++k)
        if (__any(hit & (1u << k))) byte |= (1u << k);
    if (lane == 0 && byte)
        atomicOr(&flags[jg >> 2], byte << ((jg & 3) * 8));
}

// ---------------------------------------------------------------------------
// Kernel 3: masked float4 write of sorted boxes.
// ---------------------------------------------------------------------------
__global__ __launch_bounds__(256) void nms_write_kernel(
    const float4* __restrict__ sbox, const uint32_t* __restrict__ flags,
    float4* __restrict__ out)
{
    int j = blockIdx.x * 256 + threadIdx.x;
    bool sup = (flags[j >> 5] >> (j & 31)) & 1u;
    float4 v = sbox[j];
    if (sup) { v.x = 0.0f; v.y = 0.0f; v.z = 0.0f; v.w = 0.0f; }
    out[j] = v;
}

extern "C" void kernel_launch(void* const* d_in, const int* in_sizes, int n_in,
                              void* d_out, int out_size, void* d_ws, size_t ws_size,
                              hipStream_t stream) {
    const float4*   bbox  = (const float4*)d_in[0];    // (8192,4) f32
    const uint32_t* sbits = (const uint32_t*)d_in[1];  // (8192,)  f32 bits
    float4* out = (float4*)d_out;                      // (8192,4) f32
    float4* sbox = (float4*)d_ws;                      // 128 KB
    uint32_t* flags = (uint32_t*)((float*)d_ws + 4 * NBOX);  // 1 KB

    hipLaunchKernelGGL(nms_rank_kernel, dim3(NBOX / 16), dim3(256), 0, stream,
                       bbox, sbits, sbox, flags);
    // triangular grid: 8704 wave-tasks = 2176 blocks of 4 waves
    hipLaunchKernelGGL(nms_suppress_kernel, dim3(2176), dim3(256), 0, stream,
                       sbox, flags);
    hipLaunchKernelGGL(nms_write_kernel, dim3(NBOX / 256), dim3(256), 0, stream,
                       sbox, flags, out);
}